// Round 7
// baseline (262.749 us; speedup 1.0000x reference)
//
#include <hip/hip_runtime.h>
#include <hip/hip_bf16.h>
#include <cmath>

// Problem constants (fixed by the reference)
constexpr int CB  = 8;     // batch
constexpr int CN  = 1024;  // sequence length
constexpr int CD  = 256;   // model dim
constexpr int CH  = 8;     // heads
constexpr int CDH = 32;    // head dim
constexpr int CR  = 4;     // relation types (adj value 4 = none)
constexpr int CFF = 1024;  // ffn dim
constexpr float CEPS = 1e-5f;
constexpr size_t SZH = (size_t)CB * CH * CN * CDH;  // 2M: one head-plane

#define MODE_QK    0   // scatter bf16 q/k head-major planes, +bias (cols 0..511)
#define MODE_OPROJ 1   // +bias +fp32 residual -> fp32
#define MODE_FFN1  2   // +bias, exact gelu -> bf16
#define MODE_FFN2  3   // +bias +fp32 residual -> fp32
#define MODE_VT    4   // V^T gemm (A=weights rows, B=src rows): coalesced store
                       // to [r][bh][d][N]; bias indexed by ROW (m)

typedef float v4f __attribute__((ext_vector_type(4)));
typedef short v8s __attribute__((ext_vector_type(8)));

static __device__ __forceinline__ short f2bf(float f) {
    unsigned u = __builtin_bit_cast(unsigned, f);
    u += 0x7fff + ((u >> 16) & 1);          // round-to-nearest-even
    return (short)(u >> 16);
}

static __device__ __forceinline__ void async_copy16(const void* g, void* l) {
    __builtin_amdgcn_global_load_lds(
        (const __attribute__((address_space(1))) void*)g,
        (__attribute__((address_space(3))) void*)l, 16, 0, 0);
}

// ---------------------------------------------------------------------------
// bf16 MFMA GEMM, SOFTWARE-PIPELINED K-loop (1-deep prefetch):
//   dest = epilogue(A[M,K]bf16 @ Bw[N,K]bf16)
// Per iter: __syncthreads (drains LAST iter's prefetch via compiler vmcnt(0));
// immediately issue next panel's global_load_lds into the other buffer (no
// register dep -> ds_read of current buffer does NOT wait on it); compute.
// BK=32 double-buffered: 32 KB LDS for 128x128.
// ---------------------------------------------------------------------------
template<int BM, int BN, int MODE>
__global__ __launch_bounds__(256)
void gemm_mfma(const short* __restrict__ A, const short* __restrict__ Bw,
               const float* __restrict__ biasv, const float* __restrict__ add,
               void* __restrict__ dest, int M, int K, int Nw)
{
    constexpr int WTM = BM / 2, WTN = BN / 2;
    constexpr int TM = WTM / 16, TN = WTN / 16;
    __shared__ short As[2][BM * 32];
    __shared__ short Bs[2][BN * 32];

    const int t    = threadIdx.x;
    const int lane = t & 63;
    const int w    = t >> 6;
    const int quad = lane >> 4, l15 = lane & 15;
    const int wm = w >> 1, wn = w & 1;
    const int m0 = blockIdx.x * BM, n0 = blockIdx.y * BN;

    const int srow = lane >> 2;          // 0..15 row-within-issue
    const int scol = (lane & 3) * 8;     // 8-elem chunk

    v4f acc[TM][TN];
    #pragma unroll
    for (int i = 0; i < TM; ++i)
        #pragma unroll
        for (int j = 0; j < TN; ++j) acc[i][j] = (v4f){0.f, 0.f, 0.f, 0.f};

    const int NK = K >> 5;               // number of 32-wide panels

    // stage panel `kt` into buffer `buf`
    auto stage = [&](int buf, int kt) {
        #pragma unroll
        for (int u = 0; u < BM / 64; ++u) {
            const int e0 = (w * (BM / 64) + u) * 512;
            const int row = (e0 >> 5) + srow;
            async_copy16(A + (size_t)(m0 + row) * K + kt + scol, &As[buf][e0]);
        }
        #pragma unroll
        for (int u = 0; u < BN / 64; ++u) {
            const int e0 = (w * (BN / 64) + u) * 512;
            const int row = (e0 >> 5) + srow;
            async_copy16(Bw + (size_t)(n0 + row) * K + kt + scol, &Bs[buf][e0]);
        }
    };

    stage(0, 0);                         // prologue prefetch

    for (int it = 0; it < NK; ++it) {
        __syncthreads();                 // drains prefetch for THIS iter
        if (it + 1 < NK) stage((it + 1) & 1, (it + 1) << 5);   // flies during compute

        const int buf = it & 1;
        v8s af[TM], bfr[TN];
        #pragma unroll
        for (int i = 0; i < TM; ++i)
            af[i] = *(const v8s*)&As[buf][(wm * WTM + i * 16 + l15) * 32 + quad * 8];
        #pragma unroll
        for (int j = 0; j < TN; ++j)
            bfr[j] = *(const v8s*)&Bs[buf][(wn * WTN + j * 16 + l15) * 32 + quad * 8];
        #pragma unroll
        for (int i = 0; i < TM; ++i)
            #pragma unroll
            for (int j = 0; j < TN; ++j)
                acc[i][j] = __builtin_amdgcn_mfma_f32_16x16x32_bf16(
                    af[i], bfr[j], acc[i][j], 0, 0, 0);
    }

    #pragma unroll
    for (int i = 0; i < TM; ++i) {
        #pragma unroll
        for (int j = 0; j < TN; ++j) {
            const int mb = m0 + wm * WTM + i * 16 + quad * 4;   // row of rr=0
            const int n  = n0 + wn * WTN + j * 16 + l15;
            float vals[4];
            if (MODE == MODE_VT) {
                #pragma unroll
                for (int rr = 0; rr < 4; ++rr) vals[rr] = acc[i][j][rr] + biasv[mb + rr];
            } else {
                #pragma unroll
                for (int rr = 0; rr < 4; ++rr) vals[rr] = acc[i][j][rr] + biasv[n];
            }

            if (MODE == MODE_QK) {
                const int b = mb >> 10, ii0 = mb & 1023;
                const int plane = n >> 8, nn = n & 255;
                const int h = nn >> 5, d = nn & 31;
                #pragma unroll
                for (int rr = 0; rr < 4; ++rr)
                    ((short*)dest)[(size_t)plane * SZH +
                        (((size_t)(b * CH + h)) * CN + ii0 + rr) * CDH + d] =
                        f2bf(vals[rr]);
            } else if (MODE == MODE_VT) {
                // row m -> (r,h,d); col n -> (b,ii); store [r*64+b*8+h][d][N]
                const int b = n >> 10, ii = n & 1023;
                #pragma unroll
                for (int rr = 0; rr < 4; ++rr) {
                    const int m = mb + rr;
                    const int r2 = m >> 8, hd = m & 255;
                    const int h = hd >> 5, d = hd & 31;
                    ((short*)dest)[2 * SZH +
                        (((size_t)(r2 * 64 + b * CH + h)) * CDH + d) * CN + ii] =
                        f2bf(vals[rr]);
                }
            } else if (MODE == MODE_OPROJ || MODE == MODE_FFN2) {
                #pragma unroll
                for (int rr = 0; rr < 4; ++rr) {
                    const size_t idx = (size_t)(mb + rr) * Nw + n;
                    ((float*)dest)[idx] = vals[rr] + add[idx];
                }
            } else { // MODE_FFN1: exact gelu -> bf16
                #pragma unroll
                for (int rr = 0; rr < 4; ++rr) {
                    const size_t idx = (size_t)(mb + rr) * Nw + n;
                    ((short*)dest)[idx] = f2bf(0.5f * vals[rr] *
                        (1.0f + erff(vals[rr] * 0.70710678118654752f)));
                }
            }
        }
    }
}

// ---------------------------------------------------------------------------
// One fused prep dispatch: adj->int8, src->bf16, weights -> bf16 W^T[n][k],
// biases packed.
// ---------------------------------------------------------------------------
__global__ __launch_bounds__(256)
void prep(const int* __restrict__ adj, const float* __restrict__ src,
          const float* __restrict__ Wq, const float* __restrict__ Wk,
          const float* __restrict__ Wv, const float* __restrict__ Wo,
          const float* __restrict__ W1, const float* __restrict__ W2,
          const float* __restrict__ bq, const float* __restrict__ bk,
          const float* __restrict__ bv, const float* __restrict__ bo,
          const float* __restrict__ b1, const float* __restrict__ b2,
          unsigned char* __restrict__ adj8, short* __restrict__ src_bf,
          short* __restrict__ wqkvT, short* __restrict__ woT,
          short* __restrict__ w1T, short* __restrict__ w2T,
          float* __restrict__ bpack)
{
    const int bx = blockIdx.x, t = threadIdx.x;
    if (bx < 8192) {                                   // adj cast: 2M int4
        const int i = bx * 256 + t;
        const int4 vv = ((const int4*)adj)[i];
        uchar4 c;
        c.x = (unsigned char)vv.x; c.y = (unsigned char)vv.y;
        c.z = (unsigned char)vv.z; c.w = (unsigned char)vv.w;
        ((uchar4*)adj8)[i] = c;
    } else if (bx < 10240) {                           // src cast: 512K float4
        const int i = (bx - 8192) * 256 + t;
        const float4 v = ((const float4*)src)[i];
        short4 o;
        o.x = f2bf(v.x); o.y = f2bf(v.y); o.z = f2bf(v.z); o.w = f2bf(v.w);
        ((short4*)src_bf)[i] = o;
    } else if (bx < 11776) {                           // wqkv: 1536*256
        const int idx = (bx - 10240) * 256 + t;
        const int n = idx >> 8, k = idx & 255;
        float v;
        if (n < 256)      v = Wq[k * 256 + n];
        else if (n < 512) v = Wk[k * 256 + (n - 256)];
        else { const int r = (n - 512) >> 8;
               v = Wv[((size_t)r * 256 + k) * 256 + ((n - 512) & 255)]; }
        wqkvT[idx] = f2bf(v);
    } else if (bx < 12032) {                           // wo: 256*256
        const int idx = (bx - 11776) * 256 + t;
        const int n = idx >> 8, k = idx & 255;
        woT[idx] = f2bf(Wo[k * 256 + n]);
    } else if (bx < 13056) {                           // w1: 1024*256
        const int idx = (bx - 12032) * 256 + t;
        const int n = idx >> 8, k = idx & 255;
        w1T[idx] = f2bf(W1[k * 1024 + n]);
    } else if (bx < 14080) {                           // w2: 256*1024
        const int idx = (bx - 13056) * 256 + t;
        const int n = idx >> 10, k = idx & 1023;
        w2T[idx] = f2bf(W2[k * 256 + n]);
    } else {                                           // biases: 3072
        const int idx = (bx - 14080) * 256 + t;
        float bvv;
        if (idx < 256)       bvv = bq[idx];
        else if (idx < 512)  bvv = bk[idx - 256];
        else if (idx < 1536) bvv = bv[idx - 512];
        else if (idx < 1792) bvv = bo[idx - 1536];
        else if (idx < 2816) bvv = b1[idx - 1792];
        else                 bvv = b2[idx - 2816];
        bpack[idx] = bvv;
    }
}

// ---------------------------------------------------------------------------
// Fused relational attention (UNCHANGED from round 6: 69 us, proven).
// ---------------------------------------------------------------------------
__global__ __launch_bounds__(256)
void attn_mfma(const short* __restrict__ qg, const short* __restrict__ kg,
               const short* __restrict__ vt, const unsigned char* __restrict__ adj8,
               short* __restrict__ outh)
{
    __shared__ __align__(16) short ks[64 * 32];         // K tile [j][32], DMA
    __shared__ __align__(16) short vtile[4][32][72];    // V^T tiles [r][d][j]
    __shared__ __align__(16) short ps[64][68];          // P tile [i][j]
    __shared__ __align__(16) unsigned char adjs[64][72];// adj tile [i][j]
    __shared__ int lut[64][4];                          // byte-pair -> selectors

    const int t    = threadIdx.x;
    const int lane = t & 63;
    const int w    = t >> 6;          // wave 0..3
    const int quad = lane >> 4;
    const int l15  = lane & 15;
    const int i0   = blockIdx.x * 64;
    const int h    = blockIdx.y;
    const int b    = blockIdx.z;
    const int bhh  = b * CH + h;
    const size_t bh = (size_t)bhh;

    if (t < 64) {
        const int b0 = t & 7, b1 = t >> 3;
        #pragma unroll
        for (int r = 0; r < 4; ++r) {
            const int lo = (b0 == r) ? 0x0100 : 0x0c0c;
            const int hi = (b1 == r) ? 0x0302 : 0x0c0c;
            lut[t][r] = lo | (hi << 16);
        }
    }

    const v8s qfrag = *(const v8s*)&qg[(bh * CN + i0 + 16 * w + l15) * CDH + quad * 8];

    v4f oacc[2];
    oacc[0] = (v4f){0.f, 0.f, 0.f, 0.f};
    oacc[1] = (v4f){0.f, 0.f, 0.f, 0.f};
    float plsum[4] = {0.f, 0.f, 0.f, 0.f};

    const float cs = 0.25503480f;     // (1/sqrt(32)) * log2(e)
    const int arow = 16 * w + l15;    // this lane's P/adj row (wave-private)

    const int srow = lane >> 2;            // K: row within wave-issue
    const int scol = (lane & 3) * 8;       // K: 8-elem chunk
    const int vd0  = lane >> 3;            // V: base d (0..7), +8*it
    const int vc   = (lane & 7) * 8;       // V: j chunk
    const short* vplane = vt + (((size_t)(w * 64 + bhh)) * CDH) * CN;  // wave w -> relation w
    const int aro = t >> 2;                // adj: row
    const int aco = (t & 3) * 16;          // adj: 16B chunk

    for (int jt = 0; jt < 16; ++jt) {
        const int j0 = jt * 64;
        __syncthreads();              // previous tile fully consumed

        async_copy16(kg + (bh * CN + j0 + 16 * w + srow) * CDH + scol,
                     &ks[(16 * w + srow) * 32]);
        #pragma unroll
        for (int it = 0; it < 4; ++it) {
            const int d = vd0 + 8 * it;
            const v8s vv = *(const v8s*)&vplane[(size_t)d * CN + j0 + vc];
            *(v8s*)&vtile[w][d][vc] = vv;
        }
        const int4 av = *(const int4*)&adj8[((size_t)b * CN + i0 + aro) * CN + j0 + aco];
        *(int4*)&adjs[aro][aco] = av;
        __syncthreads();

        v4f sacc[4];
        #pragma unroll
        for (int jb = 0; jb < 4; ++jb) {
            const v8s kfrag = *(const v8s*)&ks[(16 * jb + l15) * 32 + quad * 8];
            sacc[jb] = __builtin_amdgcn_mfma_f32_16x16x32_bf16(
                qfrag, kfrag, (v4f){0.f, 0.f, 0.f, 0.f}, 0, 0, 0);
        }

        #pragma unroll
        for (int rr = 0; rr < 4; ++rr) {
            const int prow = 16 * w + quad * 4 + rr;
            float p[4];
            #pragma unroll
            for (int jb = 0; jb < 4; ++jb) p[jb] = exp2f(cs * sacc[jb][rr]);
            plsum[rr] += (p[0] + p[1]) + (p[2] + p[3]);
            #pragma unroll
            for (int jb = 0; jb < 4; ++jb)
                ps[prow][16 * jb + l15] = f2bf(p[jb]);
        }

        #pragma unroll
        for (int kb = 0; kb < 2; ++kb) {
            const int2 p0 = *(const int2*)&ps[arow][32 * kb + quad * 8];
            const int2 p1 = *(const int2*)&ps[arow][32 * kb + quad * 8 + 4];
            const int2 ab = *(const int2*)&adjs[arow][32 * kb + quad * 8];
            int pf[4][4];
            #pragma unroll
            for (int half = 0; half < 2; ++half) {
                const unsigned a = (unsigned)(half ? ab.y : ab.x);
                const int P0 = half ? p1.x : p0.x;
                const int P1 = half ? p1.y : p0.y;
                const int idxA = (a & 7) | ((a >> 5) & 0x38);
                const int idxB = ((a >> 16) & 7) | ((a >> 21) & 0x38);
                const int4 selA = *(const int4*)&lut[idxA][0];
                const int4 selB = *(const int4*)&lut[idxB][0];
                pf[0][half * 2 + 0] = __builtin_amdgcn_perm(P0, P0, selA.x);
                pf[1][half * 2 + 0] = __builtin_amdgcn_perm(P0, P0, selA.y);
                pf[2][half * 2 + 0] = __builtin_amdgcn_perm(P0, P0, selA.z);
                pf[3][half * 2 + 0] = __builtin_amdgcn_perm(P0, P0, selA.w);
                pf[0][half * 2 + 1] = __builtin_amdgcn_perm(P1, P1, selB.x);
                pf[1][half * 2 + 1] = __builtin_amdgcn_perm(P1, P1, selB.y);
                pf[2][half * 2 + 1] = __builtin_amdgcn_perm(P1, P1, selB.z);
                pf[3][half * 2 + 1] = __builtin_amdgcn_perm(P1, P1, selB.w);
            }
            #pragma unroll
            for (int r = 0; r < 4; ++r) {
                const v8s pfr = __builtin_bit_cast(v8s,
                    make_int4(pf[r][0], pf[r][1], pf[r][2], pf[r][3]));
                #pragma unroll
                for (int cb = 0; cb < 2; ++cb) {
                    const v8s vfrag = *(const v8s*)&vtile[r][16 * cb + l15][32 * kb + quad * 8];
                    oacc[cb] = __builtin_amdgcn_mfma_f32_16x16x32_bf16(
                        pfr, vfrag, oacc[cb], 0, 0, 0);
                }
            }
        }
    }

    #pragma unroll
    for (int rr = 0; rr < 4; ++rr) {
        float l = plsum[rr];
        #pragma unroll
        for (int off = 1; off < 16; off <<= 1) l += __shfl_xor(l, off);
        const float inv = 1.f / l;
        const int row = i0 + 16 * w + quad * 4 + rr;
        #pragma unroll
        for (int cb = 0; cb < 2; ++cb)
            outh[((size_t)b * CN + row) * CD + h * CDH + 16 * cb + l15] =
                f2bf(oacc[cb][rr] * inv);
    }
}

// ---------------------------------------------------------------------------
// LayerNorm over last dim (256). Optionally also writes bf16 copy.
// ---------------------------------------------------------------------------
__global__ __launch_bounds__(256)
void ln_kernel(const float* __restrict__ in, const float* __restrict__ g,
               const float* __restrict__ be, float* __restrict__ out,
               short* __restrict__ outb)
{
    __shared__ float red[4];
    const int row = blockIdx.x;
    const int t = threadIdx.x;
    const float x = in[(size_t)row * CD + t];

    float s = x;
    #pragma unroll
    for (int off = 32; off > 0; off >>= 1) s += __shfl_xor(s, off);
    if ((t & 63) == 0) red[t >> 6] = s;
    __syncthreads();
    const float mean = (red[0] + red[1] + red[2] + red[3]) * (1.f / CD);
    __syncthreads();

    const float dx = x - mean;
    float s2 = dx * dx;
    #pragma unroll
    for (int off = 32; off > 0; off >>= 1) s2 += __shfl_xor(s2, off);
    if ((t & 63) == 0) red[t >> 6] = s2;
    __syncthreads();
    const float var = (red[0] + red[1] + red[2] + red[3]) * (1.f / CD);

    const float y = dx * rsqrtf(var + CEPS) * g[t] + be[t];
    out[(size_t)row * CD + t] = y;
    if (outb) outb[(size_t)row * CD + t] = f2bf(y);
}

// ---------------------------------------------------------------------------
extern "C" void kernel_launch(void* const* d_in, const int* in_sizes, int n_in,
                              void* d_out, int out_size, void* d_ws, size_t ws_size,
                              hipStream_t stream)
{
    const float* src = (const float*)d_in[0];
    const int*   adj = (const int*)d_in[1];
    const float* Wq  = (const float*)d_in[2];
    const float* bq  = (const float*)d_in[3];
    const float* Wk  = (const float*)d_in[4];
    const float* bk  = (const float*)d_in[5];
    const float* Wv  = (const float*)d_in[6];
    const float* bv  = (const float*)d_in[7];
    const float* Wo  = (const float*)d_in[8];
    const float* bo  = (const float*)d_in[9];
    const float* W1  = (const float*)d_in[10];
    const float* b1  = (const float*)d_in[11];
    const float* W2  = (const float*)d_in[12];
    const float* b2  = (const float*)d_in[13];
    const float* g1  = (const float*)d_in[14];
    const float* be1 = (const float*)d_in[15];
    const float* g2  = (const float*)d_in[16];
    const float* be2 = (const float*)d_in[17];
    float* out = (float*)d_out;

    char* wsb = (char*)d_ws;
    const size_t MB = (size_t)1 << 20;

    // workspace layout (50 MB with aliasing)
    unsigned char* adj8 = (unsigned char*)(wsb);            // [0,8) MB
    short* qkv_bf = (short*)(wsb + 8 * MB);                 // [8,32): q,k planes + vT
    short* src_bf = (short*)(wsb + 32 * MB);                // [32,36)
    short* wqkvT  = (short*)(wsb + 36 * MB);                // 768 KB
    short* woT    = (short*)(wsb + 36 * MB + 768 * 1024);   // 128 KB
    short* w1T    = (short*)(wsb + 36 * MB + 896 * 1024);   // 512 KB
    short* w2T    = (short*)(wsb + 36 * MB + 1408 * 1024);  // 512 KB
    float* bpack  = (float*)(wsb + 36 * MB + 1920 * 1024);  // 12 KB
    short* heads_bf = (short*)(wsb + 38 * MB);              // [38,42)
    float* tmp1   = (float*)(wsb + 42 * MB);                // [42,50)
    float* xres   = (float*)(wsb + 8 * MB);                 // reuse q/k (dead post-attn)
    short* x_bf   = (short*)(wsb + 32 * MB);                // reuse src_bf
    short* h1_bf  = (short*)(wsb + 16 * MB);                // reuse vT (dead post-attn)
    float* tmp2   = tmp1;

    const int M = CB * CN;        // 8192
    dim3 blk(256);

    // one fused prep dispatch (adj cast, src cast, weight transposes, biases)
    prep<<<dim3(14092), blk, 0, stream>>>(adj, src, Wq, Wk, Wv, Wo, W1, W2,
        bq, bk, bv, bo, b1, b2, adj8, src_bf, wqkvT, woT, w1T, w2T, bpack);

    // QK projection: [8192 x 512] = src_bf @ [Wq|Wk], head-major scatter
    gemm_mfma<128, 128, MODE_QK><<<dim3(M / 128, 4), blk, 0, stream>>>(
        src_bf, wqkvT, bpack, nullptr, qkv_bf, M, CD, 512);
    // V^T projection (operands swapped): [1024 x 8192] = Wv_rows @ src_bf^T
    // -> coalesced store to [r][bh][d][N]; bias indexed by row
    gemm_mfma<128, 128, MODE_VT><<<dim3(1024 / 128, M / 128), blk, 0, stream>>>(
        wqkvT + 512 * 256, src_bf, bpack + 512, nullptr, qkv_bf, 1024, CD, M);

    // fused relational MFMA attention -> bf16 heads
    attn_mfma<<<dim3(CN / 64, CH, CB), blk, 0, stream>>>(
        qkv_bf, qkv_bf + SZH, qkv_bf + 2 * SZH, adj8, heads_bf);

    // O-projection + residual, LN1
    gemm_mfma<128, 64, MODE_OPROJ><<<dim3(M / 128, CD / 64), blk, 0, stream>>>(
        heads_bf, woT, bpack + 1536, src, tmp1, M, CD, CD);
    ln_kernel<<<dim3(M), blk, 0, stream>>>(tmp1, g1, be1, xres, x_bf);

    // FFN
    gemm_mfma<128, 128, MODE_FFN1><<<dim3(M / 128, CFF / 128), blk, 0, stream>>>(
        x_bf, w1T, bpack + 1792, nullptr, h1_bf, M, CD, CFF);
    gemm_mfma<128, 64, MODE_FFN2><<<dim3(M / 128, CD / 64), blk, 0, stream>>>(
        h1_bf, w2T, bpack + 2816, xres, tmp2, M, CFF, CD);
    ln_kernel<<<dim3(M), blk, 0, stream>>>(tmp2, g2, be2, out, nullptr);
}

// Round 8
// 246.512 us; speedup vs baseline: 1.0659x; 1.0659x over previous
//
#include <hip/hip_runtime.h>
#include <hip/hip_bf16.h>
#include <cmath>

// Problem constants (fixed by the reference)
constexpr int CB  = 8;     // batch
constexpr int CN  = 1024;  // sequence length
constexpr int CD  = 256;   // model dim
constexpr int CH  = 8;     // heads
constexpr int CDH = 32;    // head dim
constexpr int CR  = 4;     // relation types (adj value 4 = none)
constexpr int CFF = 1024;  // ffn dim
constexpr float CEPS = 1e-5f;
constexpr size_t SZH = (size_t)CB * CH * CN * CDH;  // 2M: one head-plane

#define MODE_QK    0   // scatter bf16 q/k head-major planes, +bias (cols 0..511)
#define MODE_OPROJ 1   // +bias +fp32 residual -> fp32
#define MODE_FFN1  2   // +bias, tanh-gelu -> bf16
#define MODE_FFN2  3   // +bias +fp32 residual -> fp32
#define MODE_VT    4   // V^T gemm (A=weight rows, B=src rows): coalesced store
                       // to [r][bh][d][N]; bias indexed by ROW (m)

typedef float v4f __attribute__((ext_vector_type(4)));
typedef short v8s __attribute__((ext_vector_type(8)));

static __device__ __forceinline__ short f2bf(float f) {
    unsigned u = __builtin_bit_cast(unsigned, f);
    u += 0x7fff + ((u >> 16) & 1);          // round-to-nearest-even
    return (short)(u >> 16);
}

static __device__ __forceinline__ void async_copy16(const void* g, void* l) {
    __builtin_amdgcn_global_load_lds(
        (const __attribute__((address_space(1))) void*)g,
        (__attribute__((address_space(3))) void*)l, 16, 0, 0);
}

// ---------------------------------------------------------------------------
// bf16 MFMA GEMM body (device fn, dynamic LDS): epilogue(A[M,K] @ Bw[N,K])
// BM x BN tile, 4 waves 2x2, BK=32 double-buffered 1-deep prefetch.
// LDS layout: As = smem[0 .. 2*BM*32), Bs = smem[2*BM*32 .. ).
// ---------------------------------------------------------------------------
template<int BM, int BN, int MODE>
__device__ __forceinline__ void gemm_body(
    const short* __restrict__ A, const short* __restrict__ Bw,
    const float* __restrict__ biasv, const float* __restrict__ add,
    void* __restrict__ dest, int M, int K, int Nw, int bx, int by, short* smem)
{
    constexpr int WTM = BM / 2, WTN = BN / 2;
    constexpr int TM = WTM / 16, TN = WTN / 16;
    short* As = smem;                    // [2][BM*32]
    short* Bs = smem + 2 * BM * 32;      // [2][BN*32]

    const int t    = threadIdx.x;
    const int lane = t & 63;
    const int w    = t >> 6;
    const int quad = lane >> 4, l15 = lane & 15;
    const int wm = w >> 1, wn = w & 1;
    const int m0 = bx * BM, n0 = by * BN;

    const int srow = lane >> 2;          // 0..15 row-within-issue
    const int scol = (lane & 3) * 8;     // 8-elem chunk

    v4f acc[TM][TN];
    #pragma unroll
    for (int i = 0; i < TM; ++i)
        #pragma unroll
        for (int j = 0; j < TN; ++j) acc[i][j] = (v4f){0.f, 0.f, 0.f, 0.f};

    const int NK = K >> 5;               // number of 32-wide panels

    auto stage = [&](int buf, int kt) {
        #pragma unroll
        for (int u = 0; u < BM / 64; ++u) {
            const int e0 = (w * (BM / 64) + u) * 512;
            const int row = (e0 >> 5) + srow;
            async_copy16(A + (size_t)(m0 + row) * K + kt + scol,
                         &As[buf * BM * 32 + e0]);
        }
        #pragma unroll
        for (int u = 0; u < BN / 64; ++u) {
            const int e0 = (w * (BN / 64) + u) * 512;
            const int row = (e0 >> 5) + srow;
            async_copy16(Bw + (size_t)(n0 + row) * K + kt + scol,
                         &Bs[buf * BN * 32 + e0]);
        }
    };

    stage(0, 0);                         // prologue prefetch

    for (int it = 0; it < NK; ++it) {
        __syncthreads();                 // drains prefetch for THIS iter
        if (it + 1 < NK) stage((it + 1) & 1, (it + 1) << 5);

        const int buf = it & 1;
        v8s af[TM], bfr[TN];
        #pragma unroll
        for (int i = 0; i < TM; ++i)
            af[i] = *(const v8s*)&As[buf * BM * 32 +
                                     (wm * WTM + i * 16 + l15) * 32 + quad * 8];
        #pragma unroll
        for (int j = 0; j < TN; ++j)
            bfr[j] = *(const v8s*)&Bs[buf * BN * 32 +
                                      (wn * WTN + j * 16 + l15) * 32 + quad * 8];
        #pragma unroll
        for (int i = 0; i < TM; ++i)
            #pragma unroll
            for (int j = 0; j < TN; ++j)
                acc[i][j] = __builtin_amdgcn_mfma_f32_16x16x32_bf16(
                    af[i], bfr[j], acc[i][j], 0, 0, 0);
    }

    #pragma unroll
    for (int i = 0; i < TM; ++i) {
        #pragma unroll
        for (int j = 0; j < TN; ++j) {
            const int mb = m0 + wm * WTM + i * 16 + quad * 4;   // row of rr=0
            const int n  = n0 + wn * WTN + j * 16 + l15;
            float vals[4];
            if (MODE == MODE_VT) {
                #pragma unroll
                for (int rr = 0; rr < 4; ++rr) vals[rr] = acc[i][j][rr] + biasv[mb + rr];
            } else {
                #pragma unroll
                for (int rr = 0; rr < 4; ++rr) vals[rr] = acc[i][j][rr] + biasv[n];
            }

            if (MODE == MODE_QK) {
                const int b = mb >> 10, ii0 = mb & 1023;
                const int plane = n >> 8, nn = n & 255;
                const int h = nn >> 5, d = nn & 31;
                #pragma unroll
                for (int rr = 0; rr < 4; ++rr)
                    ((short*)dest)[(size_t)plane * SZH +
                        (((size_t)(b * CH + h)) * CN + ii0 + rr) * CDH + d] =
                        f2bf(vals[rr]);
            } else if (MODE == MODE_VT) {
                const int b = n >> 10, ii = n & 1023;
                #pragma unroll
                for (int rr = 0; rr < 4; ++rr) {
                    const int m = mb + rr;
                    const int r2 = m >> 8, hd = m & 255;
                    const int h = hd >> 5, d = hd & 31;
                    ((short*)dest)[2 * SZH +
                        (((size_t)(r2 * 64 + b * CH + h)) * CDH + d) * CN + ii] =
                        f2bf(vals[rr]);
                }
            } else if (MODE == MODE_OPROJ || MODE == MODE_FFN2) {
                #pragma unroll
                for (int rr = 0; rr < 4; ++rr) {
                    const size_t idx = (size_t)(mb + rr) * Nw + n;
                    ((float*)dest)[idx] = vals[rr] + add[idx];
                }
            } else { // MODE_FFN1: tanh-gelu -> bf16 (x*E/(E+1))
                #pragma unroll
                for (int rr = 0; rr < 4; ++rr) {
                    const size_t idx = (size_t)(mb + rr) * Nw + n;
                    const float xx = vals[rr];
                    const float E = exp2f(2.302217f * (xx + 0.044715f * xx * xx * xx));
                    ((short*)dest)[idx] = f2bf(xx * E / (E + 1.f));
                }
            }
        }
    }
}

template<int BM, int BN, int MODE>
__global__ __launch_bounds__(256)
void gemm_mfma(const short* __restrict__ A, const short* __restrict__ Bw,
               const float* __restrict__ biasv, const float* __restrict__ add,
               void* __restrict__ dest, int M, int K, int Nw)
{
    extern __shared__ short smem[];
    gemm_body<BM, BN, MODE>(A, Bw, biasv, add, dest, M, K, Nw,
                            blockIdx.x, blockIdx.y, smem);
}

// Fused projection dispatch: blocks 0..511 = QK (8192x512), 512..1535 = V^T
// (1024x8192, operand-swapped).  One dispatch -> 1536 blocks = 6 blocks/CU.
__global__ __launch_bounds__(256)
void proj_kernel(const short* __restrict__ src_bf, const short* __restrict__ wqkvT,
                 const float* __restrict__ bpack, short* __restrict__ qkv)
{
    extern __shared__ short smem[];
    const int g = blockIdx.x;
    if (g < 512) {
        gemm_body<64, 128, MODE_QK>(src_bf, wqkvT, bpack, nullptr, qkv,
                                    8192, 256, 512, g >> 2, g & 3, smem);
    } else {
        const int h2 = g - 512;
        gemm_body<64, 128, MODE_VT>(wqkvT + 512 * 256, src_bf, bpack + 512, nullptr,
                                    qkv, 1024, 256, 8192, h2 & 15, h2 >> 4, smem);
    }
}

// ---------------------------------------------------------------------------
// One fused prep dispatch: adj->int8, src->bf16, weights -> bf16 W^T[n][k],
// biases packed.
// ---------------------------------------------------------------------------
__global__ __launch_bounds__(256)
void prep(const int* __restrict__ adj, const float* __restrict__ src,
          const float* __restrict__ Wq, const float* __restrict__ Wk,
          const float* __restrict__ Wv, const float* __restrict__ Wo,
          const float* __restrict__ W1, const float* __restrict__ W2,
          const float* __restrict__ bq, const float* __restrict__ bk,
          const float* __restrict__ bv, const float* __restrict__ bo,
          const float* __restrict__ b1, const float* __restrict__ b2,
          unsigned char* __restrict__ adj8, short* __restrict__ src_bf,
          short* __restrict__ wqkvT, short* __restrict__ woT,
          short* __restrict__ w1T, short* __restrict__ w2T,
          float* __restrict__ bpack)
{
    const int bx = blockIdx.x, t = threadIdx.x;
    if (bx < 8192) {                                   // adj cast: 2M int4
        const int i = bx * 256 + t;
        const int4 vv = ((const int4*)adj)[i];
        uchar4 c;
        c.x = (unsigned char)vv.x; c.y = (unsigned char)vv.y;
        c.z = (unsigned char)vv.z; c.w = (unsigned char)vv.w;
        ((uchar4*)adj8)[i] = c;
    } else if (bx < 10240) {                           // src cast: 512K float4
        const int i = (bx - 8192) * 256 + t;
        const float4 v = ((const float4*)src)[i];
        short4 o;
        o.x = f2bf(v.x); o.y = f2bf(v.y); o.z = f2bf(v.z); o.w = f2bf(v.w);
        ((short4*)src_bf)[i] = o;
    } else if (bx < 11776) {                           // wqkv: 1536*256
        const int idx = (bx - 10240) * 256 + t;
        const int n = idx >> 8, k = idx & 255;
        float v;
        if (n < 256)      v = Wq[k * 256 + n];
        else if (n < 512) v = Wk[k * 256 + (n - 256)];
        else { const int r = (n - 512) >> 8;
               v = Wv[((size_t)r * 256 + k) * 256 + ((n - 512) & 255)]; }
        wqkvT[idx] = f2bf(v);
    } else if (bx < 12032) {                           // wo: 256*256
        const int idx = (bx - 11776) * 256 + t;
        const int n = idx >> 8, k = idx & 255;
        woT[idx] = f2bf(Wo[k * 256 + n]);
    } else if (bx < 13056) {                           // w1: 1024*256
        const int idx = (bx - 12032) * 256 + t;
        const int n = idx >> 8, k = idx & 255;
        w1T[idx] = f2bf(W1[k * 1024 + n]);
    } else if (bx < 14080) {                           // w2: 256*1024
        const int idx = (bx - 13056) * 256 + t;
        const int n = idx >> 10, k = idx & 1023;
        w2T[idx] = f2bf(W2[k * 256 + n]);
    } else {                                           // biases: 3072
        const int idx = (bx - 14080) * 256 + t;
        float bvv;
        if (idx < 256)       bvv = bq[idx];
        else if (idx < 512)  bvv = bk[idx - 256];
        else if (idx < 1536) bvv = bv[idx - 512];
        else if (idx < 1792) bvv = bo[idx - 1536];
        else if (idx < 2816) bvv = b1[idx - 1792];
        else                 bvv = b2[idx - 2816];
        bpack[idx] = bvv;
    }
}

// ---------------------------------------------------------------------------
// Fused relational attention (UNCHANGED from round 6: 68 us, proven).
// ---------------------------------------------------------------------------
__global__ __launch_bounds__(256)
void attn_mfma(const short* __restrict__ qg, const short* __restrict__ kg,
               const short* __restrict__ vt, const unsigned char* __restrict__ adj8,
               short* __restrict__ outh)
{
    __shared__ __align__(16) short ks[64 * 32];         // K tile [j][32], DMA
    __shared__ __align__(16) short vtile[4][32][72];    // V^T tiles [r][d][j]
    __shared__ __align__(16) short ps[64][68];          // P tile [i][j]
    __shared__ __align__(16) unsigned char adjs[64][72];// adj tile [i][j]
    __shared__ int lut[64][4];                          // byte-pair -> selectors

    const int t    = threadIdx.x;
    const int lane = t & 63;
    const int w    = t >> 6;          // wave 0..3
    const int quad = lane >> 4;
    const int l15  = lane & 15;
    const int i0   = blockIdx.x * 64;
    const int h    = blockIdx.y;
    const int b    = blockIdx.z;
    const int bhh  = b * CH + h;
    const size_t bh = (size_t)bhh;

    if (t < 64) {
        const int b0 = t & 7, b1 = t >> 3;
        #pragma unroll
        for (int r = 0; r < 4; ++r) {
            const int lo = (b0 == r) ? 0x0100 : 0x0c0c;
            const int hi = (b1 == r) ? 0x0302 : 0x0c0c;
            lut[t][r] = lo | (hi << 16);
        }
    }

    const v8s qfrag = *(const v8s*)&qg[(bh * CN + i0 + 16 * w + l15) * CDH + quad * 8];

    v4f oacc[2];
    oacc[0] = (v4f){0.f, 0.f, 0.f, 0.f};
    oacc[1] = (v4f){0.f, 0.f, 0.f, 0.f};
    float plsum[4] = {0.f, 0.f, 0.f, 0.f};

    const float cs = 0.25503480f;     // (1/sqrt(32)) * log2(e)
    const int arow = 16 * w + l15;    // this lane's P/adj row (wave-private)

    const int srow = lane >> 2;            // K: row within wave-issue
    const int scol = (lane & 3) * 8;       // K: 8-elem chunk
    const int vd0  = lane >> 3;            // V: base d (0..7), +8*it
    const int vc   = (lane & 7) * 8;       // V: j chunk
    const short* vplane = vt + (((size_t)(w * 64 + bhh)) * CDH) * CN;  // wave w -> relation w
    const int aro = t >> 2;                // adj: row
    const int aco = (t & 3) * 16;          // adj: 16B chunk

    for (int jt = 0; jt < 16; ++jt) {
        const int j0 = jt * 64;
        __syncthreads();              // previous tile fully consumed

        async_copy16(kg + (bh * CN + j0 + 16 * w + srow) * CDH + scol,
                     &ks[(16 * w + srow) * 32]);
        #pragma unroll
        for (int it = 0; it < 4; ++it) {
            const int d = vd0 + 8 * it;
            const v8s vv = *(const v8s*)&vplane[(size_t)d * CN + j0 + vc];
            *(v8s*)&vtile[w][d][vc] = vv;
        }
        const int4 av = *(const int4*)&adj8[((size_t)b * CN + i0 + aro) * CN + j0 + aco];
        *(int4*)&adjs[aro][aco] = av;
        __syncthreads();

        v4f sacc[4];
        #pragma unroll
        for (int jb = 0; jb < 4; ++jb) {
            const v8s kfrag = *(const v8s*)&ks[(16 * jb + l15) * 32 + quad * 8];
            sacc[jb] = __builtin_amdgcn_mfma_f32_16x16x32_bf16(
                qfrag, kfrag, (v4f){0.f, 0.f, 0.f, 0.f}, 0, 0, 0);
        }

        #pragma unroll
        for (int rr = 0; rr < 4; ++rr) {
            const int prow = 16 * w + quad * 4 + rr;
            float p[4];
            #pragma unroll
            for (int jb = 0; jb < 4; ++jb) p[jb] = exp2f(cs * sacc[jb][rr]);
            plsum[rr] += (p[0] + p[1]) + (p[2] + p[3]);
            #pragma unroll
            for (int jb = 0; jb < 4; ++jb)
                ps[prow][16 * jb + l15] = f2bf(p[jb]);
        }

        #pragma unroll
        for (int kb = 0; kb < 2; ++kb) {
            const int2 p0 = *(const int2*)&ps[arow][32 * kb + quad * 8];
            const int2 p1 = *(const int2*)&ps[arow][32 * kb + quad * 8 + 4];
            const int2 ab = *(const int2*)&adjs[arow][32 * kb + quad * 8];
            int pf[4][4];
            #pragma unroll
            for (int half = 0; half < 2; ++half) {
                const unsigned a = (unsigned)(half ? ab.y : ab.x);
                const int P0 = half ? p1.x : p0.x;
                const int P1 = half ? p1.y : p0.y;
                const int idxA = (a & 7) | ((a >> 5) & 0x38);
                const int idxB = ((a >> 16) & 7) | ((a >> 21) & 0x38);
                const int4 selA = *(const int4*)&lut[idxA][0];
                const int4 selB = *(const int4*)&lut[idxB][0];
                pf[0][half * 2 + 0] = __builtin_amdgcn_perm(P0, P0, selA.x);
                pf[1][half * 2 + 0] = __builtin_amdgcn_perm(P0, P0, selA.y);
                pf[2][half * 2 + 0] = __builtin_amdgcn_perm(P0, P0, selA.z);
                pf[3][half * 2 + 0] = __builtin_amdgcn_perm(P0, P0, selA.w);
                pf[0][half * 2 + 1] = __builtin_amdgcn_perm(P1, P1, selB.x);
                pf[1][half * 2 + 1] = __builtin_amdgcn_perm(P1, P1, selB.y);
                pf[2][half * 2 + 1] = __builtin_amdgcn_perm(P1, P1, selB.z);
                pf[3][half * 2 + 1] = __builtin_amdgcn_perm(P1, P1, selB.w);
            }
            #pragma unroll
            for (int r = 0; r < 4; ++r) {
                const v8s pfr = __builtin_bit_cast(v8s,
                    make_int4(pf[r][0], pf[r][1], pf[r][2], pf[r][3]));
                #pragma unroll
                for (int cb = 0; cb < 2; ++cb) {
                    const v8s vfrag = *(const v8s*)&vtile[r][16 * cb + l15][32 * kb + quad * 8];
                    oacc[cb] = __builtin_amdgcn_mfma_f32_16x16x32_bf16(
                        pfr, vfrag, oacc[cb], 0, 0, 0);
                }
            }
        }
    }

    #pragma unroll
    for (int rr = 0; rr < 4; ++rr) {
        float l = plsum[rr];
        #pragma unroll
        for (int off = 1; off < 16; off <<= 1) l += __shfl_xor(l, off);
        const float inv = 1.f / l;
        const int row = i0 + 16 * w + quad * 4 + rr;
        #pragma unroll
        for (int cb = 0; cb < 2; ++cb)
            outh[((size_t)b * CN + row) * CD + h * CDH + 16 * cb + l15] =
                f2bf(oacc[cb][rr] * inv);
    }
}

// ---------------------------------------------------------------------------
// LayerNorm over last dim (256). Optionally also writes bf16 copy.
// ---------------------------------------------------------------------------
__global__ __launch_bounds__(256)
void ln_kernel(const float* __restrict__ in, const float* __restrict__ g,
               const float* __restrict__ be, float* __restrict__ out,
               short* __restrict__ outb)
{
    __shared__ float red[4];
    const int row = blockIdx.x;
    const int t = threadIdx.x;
    const float x = in[(size_t)row * CD + t];

    float s = x;
    #pragma unroll
    for (int off = 32; off > 0; off >>= 1) s += __shfl_xor(s, off);
    if ((t & 63) == 0) red[t >> 6] = s;
    __syncthreads();
    const float mean = (red[0] + red[1] + red[2] + red[3]) * (1.f / CD);
    __syncthreads();

    const float dx = x - mean;
    float s2 = dx * dx;
    #pragma unroll
    for (int off = 32; off > 0; off >>= 1) s2 += __shfl_xor(s2, off);
    if ((t & 63) == 0) red[t >> 6] = s2;
    __syncthreads();
    const float var = (red[0] + red[1] + red[2] + red[3]) * (1.f / CD);

    const float y = dx * rsqrtf(var + CEPS) * g[t] + be[t];
    out[(size_t)row * CD + t] = y;
    if (outb) outb[(size_t)row * CD + t] = f2bf(y);
}

// ---------------------------------------------------------------------------
extern "C" void kernel_launch(void* const* d_in, const int* in_sizes, int n_in,
                              void* d_out, int out_size, void* d_ws, size_t ws_size,
                              hipStream_t stream)
{
    const float* src = (const float*)d_in[0];
    const int*   adj = (const int*)d_in[1];
    const float* Wq  = (const float*)d_in[2];
    const float* bq  = (const float*)d_in[3];
    const float* Wk  = (const float*)d_in[4];
    const float* bk  = (const float*)d_in[5];
    const float* Wv  = (const float*)d_in[6];
    const float* bv  = (const float*)d_in[7];
    const float* Wo  = (const float*)d_in[8];
    const float* bo  = (const float*)d_in[9];
    const float* W1  = (const float*)d_in[10];
    const float* b1  = (const float*)d_in[11];
    const float* W2  = (const float*)d_in[12];
    const float* b2  = (const float*)d_in[13];
    const float* g1  = (const float*)d_in[14];
    const float* be1 = (const float*)d_in[15];
    const float* g2  = (const float*)d_in[16];
    const float* be2 = (const float*)d_in[17];
    float* out = (float*)d_out;

    char* wsb = (char*)d_ws;
    const size_t MB = (size_t)1 << 20;

    // workspace layout (50 MB with aliasing)
    unsigned char* adj8 = (unsigned char*)(wsb);            // [0,8) MB
    short* qkv_bf = (short*)(wsb + 8 * MB);                 // [8,32): q,k planes + vT
    short* src_bf = (short*)(wsb + 32 * MB);                // [32,36)
    short* wqkvT  = (short*)(wsb + 36 * MB);                // 768 KB
    short* woT    = (short*)(wsb + 36 * MB + 768 * 1024);   // 128 KB
    short* w1T    = (short*)(wsb + 36 * MB + 896 * 1024);   // 512 KB
    short* w2T    = (short*)(wsb + 36 * MB + 1408 * 1024);  // 512 KB
    float* bpack  = (float*)(wsb + 36 * MB + 1920 * 1024);  // 12 KB
    short* heads_bf = (short*)(wsb + 38 * MB);              // [38,42)
    float* tmp1   = (float*)(wsb + 42 * MB);                // [42,50)
    float* xres   = (float*)(wsb + 8 * MB);                 // reuse q/k (dead post-attn)
    short* x_bf   = (short*)(wsb + 32 * MB);                // reuse src_bf
    short* h1_bf  = (short*)(wsb + 16 * MB);                // reuse vT (dead post-attn)
    float* tmp2   = tmp1;

    const int M = CB * CN;        // 8192
    dim3 blk(256);

    // one fused prep dispatch (adj cast, src cast, weight transposes, biases)
    prep<<<dim3(14092), blk, 0, stream>>>(adj, src, Wq, Wk, Wv, Wo, W1, W2,
        bq, bk, bv, bo, b1, b2, adj8, src_bf, wqkvT, woT, w1T, w2T, bpack);

    // fused QK + V^T projection: 1536 blocks (6/CU), dynamic LDS 24 KB
    proj_kernel<<<dim3(1536), blk, 24576, stream>>>(src_bf, wqkvT, bpack, qkv_bf);

    // fused relational MFMA attention -> bf16 heads
    attn_mfma<<<dim3(CN / 64, CH, CB), blk, 0, stream>>>(
        qkv_bf, qkv_bf + SZH, qkv_bf + 2 * SZH, adj8, heads_bf);

    // O-projection + residual, LN1   (BM=64,BN=64: 512 blocks)
    gemm_mfma<64, 64, MODE_OPROJ><<<dim3(M / 64, CD / 64), blk, 16384, stream>>>(
        heads_bf, woT, bpack + 1536, src, tmp1, M, CD, CD);
    ln_kernel<<<dim3(M), blk, 0, stream>>>(tmp1, g1, be1, xres, x_bf);

    // FFN1 (BM=64,BN=128: 1024 blocks), FFN2 (BM=64,BN=64: 512 blocks)
    gemm_mfma<64, 128, MODE_FFN1><<<dim3(M / 64, CFF / 128), blk, 24576, stream>>>(
        x_bf, w1T, bpack + 1792, nullptr, h1_bf, M, CD, CFF);
    gemm_mfma<64, 64, MODE_FFN2><<<dim3(M / 64, CD / 64), blk, 16384, stream>>>(
        h1_bf, w2T, bpack + 2816, xres, tmp2, M, CFF, CD);
    ln_kernel<<<dim3(M), blk, 0, stream>>>(tmp2, g2, be2, out, nullptr);
}